// Round 12
// baseline (4097.120 us; speedup 1.0000x reference)
//
#include <hip/hip_runtime.h>
#include <math.h>

// LNN: BS=16384, d=32 (n=16), HID=512. fp32 logic; M-GEMM + z2 on matrix cores.
// H = W1 D1 W1^T + M D2 M^T,  M = (W1^T diag(s1)) W2,  jac = W1 (s1*u),
// u = W2 (W3*s2), e1 = u(1-s1)/s1 so term1 = ws1T^T diag(e1) ws1T.
// out[:, :16] = qd = x[:,16:]; out[:,16:] = pinv(A) rhs  (fp64 Jacobi eig, JAX rcond).
//
// R12: z2-MFMA fusion on the R11 2-sample skeleton. R8 proved the fusion's
// NUMERICS (absmax 64.0) but spilled at the 128-reg cap; R11's 2-blocks/CU
// gives a 256-reg cap, so the 128 accumulator regs (M + z2, 2 samples x
// NT-pair) fit: peak ~215 < 256. Deletes z2's VALU loop (~3600 instr) and
// its 1MB/block W2 stream; adds 12 MFMA/KSTEP on the 23%-busy matrix pipe.
// h1-split packs (6KB) live in dead s_u/s_h1; LDS unchanged (2 blocks/CU).
// ks8 unroll 2 -> 1 (one fragment pipeline in flight).
// R11: two samples/block share all W2 streams + packs; per-sample order kept.
// R10/R7: two NT-pair passes; 4-way P3 ILP; P1 via W1T.
// R5: M-GEMM = bf16 MFMA, exact 3-way split (6 products, < fp32-ulp error).
// R2/R3: split fp64 Jacobi solve kernel (one wave/sample, 8 blocks/CU).

#define NSWEEP 5
#define JAX_RCOND 1.9073486e-5   // 10 * 16 * eps_f32

typedef unsigned int uint;
typedef unsigned short ushort;
typedef float f2 __attribute__((ext_vector_type(2)));
typedef float f4 __attribute__((ext_vector_type(4)));
typedef short bf16x8 __attribute__((ext_vector_type(8)));
typedef float f32x16 __attribute__((ext_vector_type(16)));
typedef uint uint2v __attribute__((ext_vector_type(2)));

// ---- LDS float offsets (2 samples) ----
// Region R (12288 floats = 49152 B): A-splits 2 samples x 3 planes x [32][128] bf16
//   (sample s at byte s*24576; planes at +0/+8192/+16384).
//   Overlays: MQ 2 x [32][132] f32 slot-swizzled (s*16896B); wsQ 2 x [128][32] f32
//   (s*4096 floats); Jacobi ws (fallback).
#define OFF_R    0
#define R_FLOATS 12288
#define OFF_S1   12288             // 2 x 512
#define OFF_H1   13312             // 2 x 512 (h1 -> zLo packs -> e1)
#define OFF_G2   14336             // 2 x 512 (g2 -> jac partials)
#define OFF_D2   15360             // 2 x 512
#define OFF_U    16384             // 2 x 512 (zHi/zMid packs during GEMM -> u)
#define OFF_X    17408             // 2 x 32
#define OFF_JAC  17472             // 2 x 16
#define OFF_T1   17504             // 2 x 528
#define OFF_T2   18560             // 2 x 528
#define OFF_AUG  19616             // 2 x 272 (contiguous 544)
#define SMEM_FLOATS 20160
#define SMEM_BYTES  (SMEM_FLOATS*4)   // 80640 B; 2 blocks/CU = 161280 <= 163840

// solve kernel: 592 doubles per wave, 4 waves/block
#define SOLVE_WAVE_DBL 592
#define SOLVE_SMEM_BYTES (4*SOLVE_WAVE_DBL*8)   // 18944 B -> 8 blocks/CU

#define PACK_BYTES 524288         // one split pack: 16 nt * 32 ks * 64 lanes * 16B

__device__ __forceinline__ ushort f2bf(float x) {      // fp32 -> bf16 RN-even
    uint u = __float_as_uint(x);
    return (ushort)((u + 0x7fffu + ((u >> 16) & 1u)) >> 16);
}
__device__ __forceinline__ float bf2f(ushort h) {
    return __uint_as_float(((uint)h) << 16);
}
__device__ __forceinline__ void split3(float x, ushort& h, ushort& m, ushort& l) {
    h = f2bf(x); float r1 = x - bf2f(h);
    m = f2bf(r1); float r2 = r1 - bf2f(m);
    l = f2bf(r2);
}

__device__ __forceinline__ void pairpq(int r, int m, int& p, int& q) {
    p = (m == 0) ? 0 : 1 + (m - 1 + r) % 15;
    q = 1 + (14 - m + r) % 15;
}

__device__ __forceinline__ void wave_fence() {
    __builtin_amdgcn_wave_barrier();
    __builtin_amdgcn_s_waitcnt(0);
    __builtin_amdgcn_wave_barrier();
}

// Shared fp64 Jacobi pinv solve: one wave, lane-indexed, private LDS region.
__device__ __forceinline__ void jacobi_solve_wave(
    const float* __restrict__ gaug, double* __restrict__ ws,
    float* __restrict__ outp, int lane)
{
    double* Ad  = ws;                // [16][17]
    double* Vd  = Ad + 272;          // [16][17]
    double* c8  = Vd + 272;          // [8]
    double* sn8 = c8 + 8;            // [8]
    double* il  = sn8 + 8;           // [16]
    double* yv  = il + 16;           // [16]

    for (int idx = lane; idx < 272; idx += 64) {
        const int r = idx / 17, c = idx - r*17;
        double a = 0.0;
        if (c < 16) a = 0.5 * ((double)gaug[r*17 + c] + (double)gaug[c*17 + r]);
        Ad[idx] = a;
        Vd[idx] = (c < 16 && r == c) ? 1.0 : 0.0;
    }
    wave_fence();

    for (int sweep = 0; sweep < NSWEEP; ++sweep) {
        for (int rr = 0; rr < 15; ++rr) {
            if (lane < 8) {
                int p, q; pairpq(rr, lane, p, q);
                const double app = Ad[p*17 + p], aqq = Ad[q*17 + q], apq = Ad[p*17 + q];
                double cc = 1.0, ss = 0.0;
                if (apq != 0.0) {
                    const double tau = (aqq - app) / (2.0 * apq);
                    const double tt = ((tau >= 0.0) ? 1.0 : -1.0) / (fabs(tau) + sqrt(1.0 + tau*tau));
                    cc = 1.0 / sqrt(1.0 + tt*tt);
                    ss = tt * cc;
                }
                c8[lane] = cc; sn8[lane] = ss;
            }
            wave_fence();
            #pragma unroll
            for (int k = 0; k < 2; ++k) {      // rows: A <- J^T A
                const int id = lane + 64*k;
                const int m = id >> 4, j = id & 15;
                int p, q; pairpq(rr, m, p, q);
                const double cc = c8[m], ss = sn8[m];
                const double ap = Ad[p*17 + j], aq = Ad[q*17 + j];
                Ad[p*17 + j] = cc*ap - ss*aq;
                Ad[q*17 + j] = ss*ap + cc*aq;
            }
            #pragma unroll
            for (int k = 0; k < 2; ++k) {      // V <- V J
                const int id = lane + 64*k;
                const int m = id >> 4, i = id & 15;
                int p, q; pairpq(rr, m, p, q);
                const double cc = c8[m], ss = sn8[m];
                const double vp = Vd[i*17 + p], vq = Vd[i*17 + q];
                Vd[i*17 + p] = cc*vp - ss*vq;
                Vd[i*17 + q] = ss*vp + cc*vq;
            }
            wave_fence();
            #pragma unroll
            for (int k = 0; k < 2; ++k) {      // cols: A <- A J
                const int id = lane + 64*k;
                const int m = id >> 4, i = id & 15;
                int p, q; pairpq(rr, m, p, q);
                const double cc = c8[m], ss = sn8[m];
                const double ap = Ad[i*17 + p], aq = Ad[i*17 + q];
                Ad[i*17 + p] = cc*ap - ss*aq;
                Ad[i*17 + q] = ss*ap + cc*aq;
            }
            wave_fence();
        }
    }

    if (lane == 0) {
        double mx = 0.0;
        #pragma unroll
        for (int i = 0; i < 16; ++i) mx = fmax(mx, fabs(Ad[i*17 + i]));
        const double cut = JAX_RCOND * mx;
        #pragma unroll
        for (int i = 0; i < 16; ++i) {
            const double l = Ad[i*17 + i];
            il[i] = (fabs(l) > cut) ? (1.0 / l) : 0.0;
        }
    }
    wave_fence();

    if (lane < 16) {
        double a = 0.0;
        #pragma unroll
        for (int r = 0; r < 16; ++r) a += Vd[r*17 + lane] * (double)gaug[r*17 + 16];
        yv[lane] = a;
    }
    wave_fence();

    if (lane < 16) {
        double a = 0.0;
        #pragma unroll
        for (int i = 0; i < 16; ++i) a += Vd[lane*17 + i] * (il[i] * yv[i]);
        outp[lane] = (float)a;
    }
}

// Pre-kernel: W1T[j*32+i] = W1[i*512+j]   (64 KB, L2-resident afterwards)
extern "C" __global__ void w1_transpose(const float* __restrict__ W1,
                                        float* __restrict__ W1T) {
    const int t = blockIdx.x * 256 + threadIdx.x;
    W1T[t] = W1[(t & 31) * 512 + (t >> 5)];
}

// Pre-kernel: split W2 into 3 bf16 packs in MFMA B-fragment order (32x32x16).
extern "C" __global__ void w2_pack(const float* __restrict__ W2,
                                   uint* __restrict__ pHi,
                                   uint* __restrict__ pMid,
                                   uint* __restrict__ pLo) {
    const int tid = blockIdx.x * 256 + threadIdx.x;   // 0..32767
    const int lane = tid & 63;
    const int k0 = ((tid >> 6) & 31) * 16 + (lane >> 5) * 8;
    const int n  = (tid >> 11) * 32 + (lane & 31);
    uint h[4], m[4], l[4];
    #pragma unroll
    for (int e2 = 0; e2 < 4; ++e2) {
        ushort h0, m0, l0, h1, m1, l1;
        split3(W2[(k0 + 2*e2    )*512 + n], h0, m0, l0);
        split3(W2[(k0 + 2*e2 + 1)*512 + n], h1, m1, l1);
        h[e2] = (uint)h0 | ((uint)h1 << 16);
        m[e2] = (uint)m0 | ((uint)m1 << 16);
        l[e2] = (uint)l0 | ((uint)l1 << 16);
    }
    #pragma unroll
    for (int e2 = 0; e2 < 4; ++e2) {
        pHi [tid*4 + e2] = h[e2];
        pMid[tid*4 + e2] = m[e2];
        pLo [tid*4 + e2] = l[e2];
    }
}

#define MFMA32(A, B, C) __builtin_amdgcn_mfma_f32_32x32x16_bf16((A), (B), (C), 0, 0, 0)

extern "C" __global__ __launch_bounds__(256, 2)
void lnn_kernel(const float* __restrict__ x,
                const float* __restrict__ W1,
                const float* __restrict__ W1T,
                const float* __restrict__ b1,
                const float* __restrict__ W2, const float* __restrict__ b2,
                const float* __restrict__ W3,
                float* __restrict__ out,
                float* __restrict__ aug_g,
                const uint* __restrict__ pHi,
                const uint* __restrict__ pMid,
                const uint* __restrict__ pLo,
                const int solveInMain)
{
    const int b0 = blockIdx.x * 2;       // two samples: b0, b0+1
    const int t = threadIdx.x;
    const int lane = t & 63;
    const int w = t >> 6;

    extern __shared__ float sm[];
    char*  A8    = (char*)sm;          // A-splits, sample s at +s*24576
    float* s_ws  = sm + OFF_R;         // wsQ, sample s at +s*4096 floats
    char*  Mq8   = (char*)sm;          // MQ, sample s at +s*16896 bytes
    float* s_s1  = sm + OFF_S1;        // +s*512
    float* s_h1  = sm + OFF_H1;        // +s*512
    float* s_g2  = sm + OFF_G2;        // +s*512
    float* s_d2  = sm + OFF_D2;        // +s*512
    float* s_u   = sm + OFF_U;         // +s*512
    float* s_x   = sm + OFF_X;         // +s*32
    float* s_jac = sm + OFF_JAC;       // +s*16
    float* s_T1  = sm + OFF_T1;        // +s*528
    float* s_T2  = sm + OFF_T2;        // +s*528
    float* s_aug = sm + OFF_AUG;       // +s*272 (contiguous 544)
    // h1-split packs during GEMM (dead space): zHi s at zB+s*1024,
    // zMid s at zB+2048+s*1024, zLo s at zLoB+s*1024.
    char*  zB   = (char*)s_u;
    char*  zLoB = (char*)s_h1;

    // ---- P0 ----
    if (t < 64) s_x[t] = x[b0*32 + t];
    if (t < 32) {
        const int s = t >> 4, i = t & 15;
        out[(b0+s)*32 + i] = x[(b0+s)*32 + 16 + i];
    }
    __syncthreads();

    // ---- P1: z1 -> s1, h1 (coalesced W1T f4 reads; ascending-i order) ----
    #pragma unroll
    for (int rep = 0; rep < 4; ++rep) {
        const int s = rep >> 1;
        const int j = t + (rep & 1)*256;
        float z = b1[j];
        const f4* wt = (const f4*)(W1T + j*32);
        const float* xs = s_x + s*32;
        #pragma unroll
        for (int i4 = 0; i4 < 8; ++i4) {
            const f4 wv = wt[i4];
            z = fmaf(xs[i4*4 + 0], wv.x, z);
            z = fmaf(xs[i4*4 + 1], wv.y, z);
            z = fmaf(xs[i4*4 + 2], wv.z, z);
            z = fmaf(xs[i4*4 + 3], wv.w, z);
        }
        const float e = expf(-fabsf(z));
        const float sg = (z >= 0.f) ? 1.f/(1.f+e) : e/(1.f+e);
        s_s1[s*512 + j] = sg;
        s_h1[s*512 + j] = fmaxf(z, 0.f) + log1pf(e);
    }
    __syncthreads();

    // ---- h1-split staging: bf16 packs for z2 A-frags (read all, barrier, write) ----
    {
        const float a0 = s_h1[2*t],       c0v = s_h1[2*t + 1];
        const float a1 = s_h1[512 + 2*t], c1v = s_h1[512 + 2*t + 1];
        __syncthreads();   // every h1 value read by its owner before overwrite
        ushort ha, ma, la, hc, mc, lc;
        split3(a0, ha, ma, la); split3(c0v, hc, mc, lc);
        ((uint*)(zB + 0))[t]    = (uint)ha | ((uint)hc << 16);
        ((uint*)(zB + 2048))[t] = (uint)ma | ((uint)mc << 16);
        ((uint*)(zLoB + 0))[t]  = (uint)la | ((uint)lc << 16);
        split3(a1, ha, ma, la); split3(c1v, hc, mc, lc);
        ((uint*)(zB + 1024))[t] = (uint)ha | ((uint)hc << 16);
        ((uint*)(zB + 3072))[t] = (uint)ma | ((uint)mc << 16);
        ((uint*)(zLoB + 1024))[t] = (uint)la | ((uint)lc << 16);
    }

    const int i5 = 16 + (t >> 4);
    const int c5 = 2 * (t & 15);

    // ---- P2+z2+P7, two NT-pair passes; 2 samples share every B-fragment ----
    float h0acc[2] = {0.f, 0.f}, h1acc[2] = {0.f, 0.f};
    {
        const f4* W1v4 = (const f4*)W1;
        const f4* s1v4 = (const f4*)s_s1;
        const bf16x8* pHiV  = (const bf16x8*)pHi;
        const bf16x8* pMidV = (const bf16x8*)pMid;
        const bf16x8* pLoV  = (const bf16x8*)pLo;
        const int arow = lane & 31;
        const uint abase = (uint)arow * 256u;
        const uint aswz = (uint)(arow & 15);
        const uint kbyte = (uint)((lane >> 5) << 4);
        const int rowadd = 4 * (lane >> 5);
        const int cl = lane & 31;
        const uint swi = (uint)((i5 >> 1) & 7);
        const uint swc = (uint)((c5 >> 1) & 7);

        #pragma unroll 1
        for (int half = 0; half < 2; ++half) {
            f32x16 acc00{}, acc01{}, acc10{}, acc11{};   // M: [sample][NT-of-pair]
            f32x16 az00{}, az01{}, az10{}, az11{};       // z2: [sample][NT-of-pair]
            const int NT0 = 2*half, NT1 = 2*half + 1;

            // GEMM pass: 4 quarters of K
            #pragma unroll 1
            for (int q = 0; q < 4; ++q) {
                __syncthreads();   // prior region-R readers + z-pack writes done
                // stage A-splits for both samples (W1 quarter loaded once)
                #pragma unroll
                for (int r = 0; r < 4; ++r) {
                    const int f = r*256 + t;
                    const int i = f >> 5, k4 = f & 31;
                    const f4 wv = W1v4[i*128 + q*32 + k4];
                    const uint off = (uint)i*256u + (((uint)k4*8u) ^ (((uint)(i & 15)) << 4));
                    #pragma unroll
                    for (int s = 0; s < 2; ++s) {
                        const f4 sv = s1v4[s*128 + q*32 + k4];
                        ushort h[4], m[4], l[4];
                        split3(wv.x*sv.x, h[0], m[0], l[0]);
                        split3(wv.y*sv.y, h[1], m[1], l[1]);
                        split3(wv.z*sv.z, h[2], m[2], l[2]);
                        split3(wv.w*sv.w, h[3], m[3], l[3]);
                        uint2v vh = { (uint)h[0] | ((uint)h[1]<<16), (uint)h[2] | ((uint)h[3]<<16) };
                        uint2v vm = { (uint)m[0] | ((uint)m[1]<<16), (uint)m[2] | ((uint)m[3]<<16) };
                        uint2v vl = { (uint)l[0] | ((uint)l[1]<<16), (uint)l[2] | ((uint)l[3]<<16) };
                        char* base = A8 + s*24576;
                        *(uint2v*)(base + off)         = vh;
                        *(uint2v*)(base + 8192 + off)  = vm;
                        *(uint2v*)(base + 16384 + off) = vl;
                    }
                }
                __syncthreads();

                #pragma unroll 1
                for (int ks8 = 0; ks8 < 8; ++ks8) {
                    const uint slot = (uint)(ks8*2 + (lane >> 5));
                    const uint aoff = abase + ((slot ^ aswz) << 4);
                    const bf16x8 aHi0  = *(const bf16x8*)(A8 + aoff);
                    const bf16x8 aMid0 = *(const bf16x8*)(A8 + 8192 + aoff);
                    const bf16x8 aLo0  = *(const bf16x8*)(A8 + 16384 + aoff);
                    const bf16x8 aHi1  = *(const bf16x8*)(A8 + 24576 + aoff);
                    const bf16x8 aMid1 = *(const bf16x8*)(A8 + 24576 + 8192 + aoff);
                    const bf16x8 aLo1  = *(const bf16x8*)(A8 + 24576 + 16384 + aoff);
                    const uint zoff = (uint)(q*256 + ks8*32) + kbyte;
                    const bf16x8 zHi0  = *(const bf16x8*)(zB + zoff);
                    const bf16x8 zHi1  = *(const bf16x8*)(zB + 1024 + zoff);
                    const bf16x8 zMid0 = *(const bf16x8*)(zB + 2048 + zoff);
                    const bf16x8 zMid1 = *(const bf16x8*)(zB + 3072 + zoff);
                    const bf16x8 zLo0  = *(const bf16x8*)(zLoB + zoff);
                    const bf16x8 zLo1  = *(const bf16x8*)(zLoB + 1024 + zoff);
                    const int pbase = (w*128 + q*8 + ks8)*64 + lane;
                    #define KSTEP(A0, A1, Z0, Z1, NT) { \
                        const bf16x8 bHi  = pHiV [pbase + (NT)*2048]; \
                        const bf16x8 bMid = pMidV[pbase + (NT)*2048]; \
                        const bf16x8 bLo  = pLoV [pbase + (NT)*2048]; \
                        A0 = MFMA32(aHi0,  bHi,  A0); \
                        A0 = MFMA32(aHi0,  bMid, A0); \
                        A0 = MFMA32(aMid0, bHi,  A0); \
                        A0 = MFMA32(aMid0, bMid, A0); \
                        A0 = MFMA32(aHi0,  bLo,  A0); \
                        A0 = MFMA32(aLo0,  bHi,  A0); \
                        A1 = MFMA32(aHi1,  bHi,  A1); \
                        A1 = MFMA32(aHi1,  bMid, A1); \
                        A1 = MFMA32(aMid1, bHi,  A1); \
                        A1 = MFMA32(aMid1, bMid, A1); \
                        A1 = MFMA32(aHi1,  bLo,  A1); \
                        A1 = MFMA32(aLo1,  bHi,  A1); \
                        Z0 = MFMA32(zHi0,  bHi,  Z0); \
                        Z0 = MFMA32(zHi0,  bMid, Z0); \
                        Z0 = MFMA32(zMid0, bHi,  Z0); \
                        Z0 = MFMA32(zMid0, bMid, Z0); \
                        Z0 = MFMA32(zHi0,  bLo,  Z0); \
                        Z0 = MFMA32(zLo0,  bHi,  Z0); \
                        Z1 = MFMA32(zHi1,  bHi,  Z1); \
                        Z1 = MFMA32(zHi1,  bMid, Z1); \
                        Z1 = MFMA32(zMid1, bHi,  Z1); \
                        Z1 = MFMA32(zMid1, bMid, Z1); \
                        Z1 = MFMA32(zHi1,  bLo,  Z1); \
                        Z1 = MFMA32(zLo1,  bHi,  Z1); }
                    KSTEP(acc00, acc10, az00, az10, NT0)
                    KSTEP(acc01, acc11, az01, az11, NT1)
                    #undef KSTEP
                }
            }

            // z2 extract -> g2, d2 for this half's columns (lanes 0-31: row 0)
            if (lane < 32) {
                const int c0g = w*128 + NT0*32 + lane;
                const int c1g = c0g + 32;
                const float bz0 = b2[c0g], bz1 = b2[c1g];
                const float w30 = W3[c0g], w31 = W3[c1g];
                {   // sample 0
                    const float z0 = az00[0] + bz0;
                    const float z1 = az01[0] + bz1;
                    const float e0 = expf(-fabsf(z0));
                    const float sg0 = (z0 >= 0.f) ? 1.f/(1.f+e0) : e0/(1.f+e0);
                    const float e1v = expf(-fabsf(z1));
                    const float sg1 = (z1 >= 0.f) ? 1.f/(1.f+e1v) : e1v/(1.f+e1v);
                    s_g2[c0g] = w30 * sg0;
                    s_d2[c0g] = w30 * sg0 * (1.f - sg0);
                    s_g2[c1g] = w31 * sg1;
                    s_d2[c1g] = w31 * sg1 * (1.f - sg1);
                }
                {   // sample 1
                    const float z0 = az10[0] + bz0;
                    const float z1 = az11[0] + bz1;
                    const float e0 = expf(-fabsf(z0));
                    const float sg0 = (z0 >= 0.f) ? 1.f/(1.f+e0) : e0/(1.f+e0);
                    const float e1v = expf(-fabsf(z1));
                    const float sg1 = (z1 >= 0.f) ? 1.f/(1.f+e1v) : e1v/(1.f+e1v);
                    s_g2[512 + c0g] = w30 * sg0;
                    s_d2[512 + c0g] = w30 * sg0 * (1.f - sg0);
                    s_g2[512 + c1g] = w31 * sg1;
                    s_d2[512 + c1g] = w31 * sg1 * (1.f - sg1);
                }
            }
            __syncthreads();   // d2 visible; A-split reads done before MQ overwrite

            // P7 half-round: panels p ascending, qq in [half*16, half*16+16)
            for (int p = 0; p < 4; ++p) {
                if (w == p) {
                    #define WRFRAG(ACC, SOFF, NT) { \
                        _Pragma("unroll") \
                        for (int r = 0; r < 16; ++r) { \
                            const int row = (r & 3) + 8*(r >> 2) + rowadd; \
                            const int col = (NT)*32 + cl; \
                            const uint slot = ((uint)(col >> 2)) ^ ((uint)((row >> 1) & 7)); \
                            *(float*)(Mq8 + (SOFF) + row*528 + (slot << 4) + ((col & 3) << 2)) = ACC[r]; \
                        } }
                    WRFRAG(acc00, 0, NT0)
                    WRFRAG(acc01, 0, NT1)
                    WRFRAG(acc10, 16896, NT0)
                    WRFRAG(acc11, 16896, NT1)
                    #undef WRFRAG
                }
                __syncthreads();
                #pragma unroll
                for (int s = 0; s < 2; ++s) {
                    const f4* d2q = (const f4*)(s_d2 + s*512);
                    const char* MiB = Mq8 + s*16896 + i5*528;
                    const char* MaB = Mq8 + s*16896 + c5*528;
                    const char* MbB = Mq8 + s*16896 + (c5+1)*528;
                    float h0 = h0acc[s], h1v = h1acc[s];
                    for (int qq = half*16; qq < half*16 + 16; ++qq) {
                        const f4 d  = d2q[p*32 + qq];
                        const f4 mi = *(const f4*)(MiB + (((uint)qq ^ swi) << 4));
                        const f4 ma = *(const f4*)(MaB + (((uint)qq ^ swc) << 4));
                        const f4 mb = *(const f4*)(MbB + (((uint)qq ^ swc) << 4));
                        float tt;
                        tt = mi.x*d.x; h0 = fmaf(tt, ma.x, h0); h1v = fmaf(tt, mb.x, h1v);
                        tt = mi.y*d.y; h0 = fmaf(tt, ma.y, h0); h1v = fmaf(tt, mb.y, h1v);
                        tt = mi.z*d.z; h0 = fmaf(tt, ma.z, h0); h1v = fmaf(tt, mb.z, h1v);
                        tt = mi.w*d.w; h0 = fmaf(tt, ma.w, h0); h1v = fmaf(tt, mb.w, h1v);
                    }
                    h0acc[s] = h0; h1acc[s] = h1v;
                }
                __syncthreads();   // reads done before next panel/half overwrites
            }
        }
        #pragma unroll
        for (int s = 0; s < 2; ++s) {
            s_T2[s*528 + (i5-16)*33 + c5]     = h0acc[s];
            s_T2[s*528 + (i5-16)*33 + c5 + 1] = h1acc[s];
        }
    }
    __syncthreads();

    // ---- P3: u[j] = W2[j,:] . g2 (4-way ILP x 2 samples; u overwrites z-packs) ----
    {
        float g2a[8], g2b[8];
        {
            const float4 ga = *(const float4*)(s_g2 + lane*8);
            const float4 gb = *(const float4*)(s_g2 + lane*8 + 4);
            g2a[0]=ga.x; g2a[1]=ga.y; g2a[2]=ga.z; g2a[3]=ga.w;
            g2a[4]=gb.x; g2a[5]=gb.y; g2a[6]=gb.z; g2a[7]=gb.w;
            const float4 gc = *(const float4*)(s_g2 + 512 + lane*8);
            const float4 gd = *(const float4*)(s_g2 + 512 + lane*8 + 4);
            g2b[0]=gc.x; g2b[1]=gc.y; g2b[2]=gc.z; g2b[3]=gc.w;
            g2b[4]=gd.x; g2b[5]=gd.y; g2b[6]=gd.z; g2b[7]=gd.w;
        }
        for (int jj = 0; jj < 32; ++jj) {
            float pr0[4], pr1[4];
            #pragma unroll
            for (int s4 = 0; s4 < 4; ++s4) {
                const int j = w*128 + jj + s4*32;
                const float4 ra = *(const float4*)(W2 + j*512 + lane*8);
                const float4 rb = *(const float4*)(W2 + j*512 + lane*8 + 4);
                float p0 = ra.x*g2a[0];
                p0 = fmaf(ra.y, g2a[1], p0); p0 = fmaf(ra.z, g2a[2], p0); p0 = fmaf(ra.w, g2a[3], p0);
                p0 = fmaf(rb.x, g2a[4], p0); p0 = fmaf(rb.y, g2a[5], p0);
                p0 = fmaf(rb.z, g2a[6], p0); p0 = fmaf(rb.w, g2a[7], p0);
                pr0[s4] = p0;
                float p1 = ra.x*g2b[0];
                p1 = fmaf(ra.y, g2b[1], p1); p1 = fmaf(ra.z, g2b[2], p1); p1 = fmaf(ra.w, g2b[3], p1);
                p1 = fmaf(rb.x, g2b[4], p1); p1 = fmaf(rb.y, g2b[5], p1);
                p1 = fmaf(rb.z, g2b[6], p1); p1 = fmaf(rb.w, g2b[7], p1);
                pr1[s4] = p1;
            }
            #pragma unroll
            for (int off = 32; off >= 1; off >>= 1) {
                #pragma unroll
                for (int s4 = 0; s4 < 4; ++s4) {
                    pr0[s4] += __shfl_xor(pr0[s4], off);
                    pr1[s4] += __shfl_xor(pr1[s4], off);
                }
            }
            if (lane == 0) {
                #pragma unroll
                for (int s4 = 0; s4 < 4; ++s4) {
                    s_u[w*128 + jj + s4*32]       = pr0[s4];
                    s_u[512 + w*128 + jj + s4*32] = pr1[s4];
                }
            }
        }
    }
    __syncthreads();

    // ---- P4e: e1 = u(1-s1)/s1 into s_h1 (h1/zLo dead) ----
    #pragma unroll
    for (int rep = 0; rep < 4; ++rep) {
        const int j = (rep >> 1)*512 + t + (rep & 1)*256;
        const float uj = s_u[j], sv = s_s1[j];
        s_h1[j] = uj * (1.f - sv) / sv;
    }

    // ---- P4/P5 quarter-staged: jac partials + term1 (both samples) ----
    {
        const f4* W1Tv4 = (const f4*)W1T;
        float jacp[2] = {0.f, 0.f};
        float t1a[2] = {0.f, 0.f}, t1b[2] = {0.f, 0.f};

        for (int q = 0; q < 4; ++q) {
            __syncthreads();   // q=0: e1 writes visible; q>0: wsQ reads done
            #pragma unroll
            for (int r = 0; r < 4; ++r) {
                const int f = r*256 + t;
                const f4 wv = W1Tv4[q*1024 + f];
                #pragma unroll
                for (int s = 0; s < 2; ++s) {
                    const float sv = s_s1[s*512 + q*128 + (f >> 3)];
                    f4 v = wv;
                    v.x*=sv; v.y*=sv; v.z*=sv; v.w*=sv;
                    ((f4*)(s_ws + s*4096))[f] = v;
                }
            }
            __syncthreads();

            if (w == q) {
                const int i  = t & 15;
                const int jb = (lane >> 4) * 32;
                #pragma unroll
                for (int s = 0; s < 2; ++s) {
                    const float* wsp = s_ws + s*4096;
                    const float* up  = s_u + s*512 + q*128;
                    float jp = jacp[s];
                    #pragma unroll 8
                    for (int jj = 0; jj < 32; ++jj)
                        jp = fmaf(wsp[(jb+jj)*32 + i], up[jb + jj], jp);
                    jacp[s] = jp;
                }
            }

            #pragma unroll
            for (int s = 0; s < 2; ++s) {
                const float* wsp = s_ws + s*4096;
                const float* ep  = s_h1 + s*512 + q*128;
                float a = t1a[s], bv = t1b[s];
                #pragma unroll 4
                for (int jj = 0; jj < 128; ++jj) {
                    const float e   = ep[jj];
                    const float wsi = wsp[jj*32 + i5];
                    const f2 wc = *(const f2*)(wsp + jj*32 + c5);
                    const float tt  = wsi * e;
                    a  = fmaf(tt, wc.x, a);
                    bv = fmaf(tt, wc.y, bv);
                }
                t1a[s] = a; t1b[s] = bv;
            }
        }
        #pragma unroll
        for (int s = 0; s < 2; ++s) {
            s_T1[s*528 + (i5-16)*33 + c5]     = t1a[s];
            s_T1[s*528 + (i5-16)*33 + c5 + 1] = t1b[s];
            s_g2[s*512 + (t>>4)*16 + (t&15)]  = jacp[s];   // g2 dead after P3
        }
    }
    __syncthreads();

    // ---- fold jac + P8 A-part (disjoint writes) ----
    if (t < 32) {
        const int s = t >> 4, i = t & 15;
        float p = 0.f;
        #pragma unroll
        for (int seg = 0; seg < 16; ++seg) p += s_g2[s*512 + seg*16 + i];
        s_jac[s*16 + i] = p;
    }
    {
        const int r = t >> 4, c = t & 15;
        #pragma unroll
        for (int s = 0; s < 2; ++s)
            s_aug[s*272 + r*17 + c] = s_T1[s*528 + r*33 + 16 + c] + s_T2[s*528 + r*33 + 16 + c];
    }
    __syncthreads();

    // ---- P8 rhs ----
    if (t < 32) {
        const int s = t >> 4, i = t & 15;
        float p = s_jac[s*16 + i];
        #pragma unroll
        for (int c = 0; c < 16; ++c)
            p -= (s_T1[s*528 + i*33 + c] + s_T2[s*528 + i*33 + c]) * s_x[s*32 + 16 + c];
        s_aug[s*272 + i*17 + 16] = p;
    }
    __syncthreads();

    if (!solveInMain) {
        // contiguous 544-float store (both samples)
        aug_g[b0*272 + t]       = s_aug[t];
        aug_g[b0*272 + 256 + t] = s_aug[256 + t];
        if (t < 32) aug_g[b0*272 + 512 + t] = s_aug[512 + t];
        return;
    }

    // Fallback: waves 0,1 solve samples 0,1
    if (w >= 2) return;
    jacobi_solve_wave(s_aug + w*272, (double*)sm + w*SOLVE_WAVE_DBL,
                      out + (b0+w)*32 + 16, lane);
}

extern "C" __global__ __launch_bounds__(256, 8)
void lnn_solve(const float* __restrict__ aug_g, float* __restrict__ out)
{
    const int t = threadIdx.x;
    const int lane = t & 63;
    const int w = t >> 6;
    const int b = blockIdx.x * 4 + w;

    extern __shared__ double dsm[];
    jacobi_solve_wave(aug_g + b*272, dsm + w*SOLVE_WAVE_DBL, out + b*32 + 16, lane);
}

extern "C" void kernel_launch(void* const* d_in, const int* in_sizes, int n_in,
                              void* d_out, int out_size, void* d_ws, size_t ws_size,
                              hipStream_t stream) {
    const float* x  = (const float*)d_in[0];
    const float* W1 = (const float*)d_in[1];
    const float* b1 = (const float*)d_in[2];
    const float* W2 = (const float*)d_in[3];
    const float* b2 = (const float*)d_in[4];
    const float* W3 = (const float*)d_in[5];
    float* out = (float*)d_out;

    float* W1T = (float*)d_ws;                             // 64 KB
    uint*  pHi  = (uint*)((char*)d_ws + 65536);
    uint*  pMid = (uint*)((char*)d_ws + 65536 + PACK_BYTES);
    uint*  pLo  = (uint*)((char*)d_ws + 65536 + 2*PACK_BYTES);
    float* aug  = (float*)((char*)d_ws + 65536 + 3*PACK_BYTES);
    const int bs = in_sizes[0] / 32;

    const size_t need = 65536 + 3*(size_t)PACK_BYTES + (size_t)bs * 272 * 4;
    const int solveInMain = (ws_size < need) ? 1 : 0;

    hipFuncSetAttribute((const void*)lnn_kernel,
                        hipFuncAttributeMaxDynamicSharedMemorySize, SMEM_BYTES);
    w1_transpose<<<dim3(64), dim3(256), 0, stream>>>(W1, W1T);
    w2_pack<<<dim3(128), dim3(256), 0, stream>>>(W2, pHi, pMid, pLo);
    lnn_kernel<<<dim3(bs/2), dim3(256), SMEM_BYTES, stream>>>(
        x, W1, W1T, b1, W2, b2, W3, out, aug, pHi, pMid, pLo, solveInMain);
    if (!solveInMain)
        lnn_solve<<<dim3(bs/4), dim3(256), SOLVE_SMEM_BYTES, stream>>>(aug, out);
}

// Round 13
// 3277.672 us; speedup vs baseline: 1.2500x; 1.2500x over previous
//
#include <hip/hip_runtime.h>
#include <math.h>

// LNN: BS=16384, d=32 (n=16), HID=512. fp32 logic; M-GEMM on matrix cores.
// H = W1 D1 W1^T + M D2 M^T,  M = (W1^T diag(s1)) W2,  jac = W1 (s1*u),
// u = W2 (W3*s2), e1 = u(1-s1)/s1 so term1 = ws1T^T diag(e1) ws1T.
// out[:, :16] = qd = x[:,16:]; out[:,16:] = pinv(A) rhs  (fp64 Jacobi eig, JAX rcond).
//
// R13: revert R12's z2-MFMA fusion (broadcast trick wastes 32x of the matrix
// pipe; dur 3360->4097. Refuted twice - rejected). Keep R11 skeleton; apply
// single-pass M-GEMM: all 4 NT accumulators x 2 samples (128 acc regs) live
// at once - feasible ONLY at the 2-blocks/CU 256-reg cap (R12 proved ~190
// live regs don't spill). Halves A-staging (4 quarters, -128 split3/thread),
// halves GEMM barriers (8) and P7 panel barriers (8). term2 per-panel sum
// returns to full-32-qq order (= R6's verified order, absmax 128 < 345.6).
// z2 = exact VALU loop (R11). All other phases identical to R11.
// R11: two samples/block share all W2 streams + packs; per-sample order kept.
// R10/R7: 4-way P3 ILP; P1 via W1T.
// R5: M-GEMM = bf16 MFMA, exact 3-way split (6 products, < fp32-ulp error).
// R2/R3: split fp64 Jacobi solve kernel (one wave/sample, 8 blocks/CU).

#define NSWEEP 5
#define JAX_RCOND 1.9073486e-5   // 10 * 16 * eps_f32

typedef unsigned int uint;
typedef unsigned short ushort;
typedef float f2 __attribute__((ext_vector_type(2)));
typedef float f4 __attribute__((ext_vector_type(4)));
typedef short bf16x8 __attribute__((ext_vector_type(8)));
typedef float f32x16 __attribute__((ext_vector_type(16)));
typedef uint uint2v __attribute__((ext_vector_type(2)));

// ---- LDS float offsets (2 samples) ----
// Region R (12288 floats = 49152 B): A-splits 2 samples x 3 planes x [32][128] bf16
//   (sample s at byte s*24576; planes at +0/+8192/+16384).
//   Overlays: MQ 2 x [32][132] f32 slot-swizzled (s*16896B); wsQ 2 x [128][32] f32
//   (s*4096 floats); Jacobi ws (fallback).
#define OFF_R    0
#define R_FLOATS 12288
#define OFF_S1   12288             // 2 x 512
#define OFF_H1   13312             // 2 x 512 (h1 -> e1)
#define OFF_G2   14336             // 2 x 512 (g2 -> jac partials)
#define OFF_D2   15360             // 2 x 512
#define OFF_U    16384             // 2 x 512
#define OFF_X    17408             // 2 x 32
#define OFF_JAC  17472             // 2 x 16
#define OFF_T1   17504             // 2 x 528
#define OFF_T2   18560             // 2 x 528
#define OFF_AUG  19616             // 2 x 272 (contiguous 544)
#define SMEM_FLOATS 20160
#define SMEM_BYTES  (SMEM_FLOATS*4)   // 80640 B; 2 blocks/CU = 161280 <= 163840

// solve kernel: 592 doubles per wave, 4 waves/block
#define SOLVE_WAVE_DBL 592
#define SOLVE_SMEM_BYTES (4*SOLVE_WAVE_DBL*8)   // 18944 B -> 8 blocks/CU

#define PACK_BYTES 524288         // one split pack: 16 nt * 32 ks * 64 lanes * 16B

__device__ __forceinline__ ushort f2bf(float x) {      // fp32 -> bf16 RN-even
    uint u = __float_as_uint(x);
    return (ushort)((u + 0x7fffu + ((u >> 16) & 1u)) >> 16);
}
__device__ __forceinline__ float bf2f(ushort h) {
    return __uint_as_float(((uint)h) << 16);
}
__device__ __forceinline__ void split3(float x, ushort& h, ushort& m, ushort& l) {
    h = f2bf(x); float r1 = x - bf2f(h);
    m = f2bf(r1); float r2 = r1 - bf2f(m);
    l = f2bf(r2);
}

__device__ __forceinline__ void pairpq(int r, int m, int& p, int& q) {
    p = (m == 0) ? 0 : 1 + (m - 1 + r) % 15;
    q = 1 + (14 - m + r) % 15;
}

__device__ __forceinline__ void wave_fence() {
    __builtin_amdgcn_wave_barrier();
    __builtin_amdgcn_s_waitcnt(0);
    __builtin_amdgcn_wave_barrier();
}

// Shared fp64 Jacobi pinv solve: one wave, lane-indexed, private LDS region.
__device__ __forceinline__ void jacobi_solve_wave(
    const float* __restrict__ gaug, double* __restrict__ ws,
    float* __restrict__ outp, int lane)
{
    double* Ad  = ws;                // [16][17]
    double* Vd  = Ad + 272;          // [16][17]
    double* c8  = Vd + 272;          // [8]
    double* sn8 = c8 + 8;            // [8]
    double* il  = sn8 + 8;           // [16]
    double* yv  = il + 16;           // [16]

    for (int idx = lane; idx < 272; idx += 64) {
        const int r = idx / 17, c = idx - r*17;
        double a = 0.0;
        if (c < 16) a = 0.5 * ((double)gaug[r*17 + c] + (double)gaug[c*17 + r]);
        Ad[idx] = a;
        Vd[idx] = (c < 16 && r == c) ? 1.0 : 0.0;
    }
    wave_fence();

    for (int sweep = 0; sweep < NSWEEP; ++sweep) {
        for (int rr = 0; rr < 15; ++rr) {
            if (lane < 8) {
                int p, q; pairpq(rr, lane, p, q);
                const double app = Ad[p*17 + p], aqq = Ad[q*17 + q], apq = Ad[p*17 + q];
                double cc = 1.0, ss = 0.0;
                if (apq != 0.0) {
                    const double tau = (aqq - app) / (2.0 * apq);
                    const double tt = ((tau >= 0.0) ? 1.0 : -1.0) / (fabs(tau) + sqrt(1.0 + tau*tau));
                    cc = 1.0 / sqrt(1.0 + tt*tt);
                    ss = tt * cc;
                }
                c8[lane] = cc; sn8[lane] = ss;
            }
            wave_fence();
            #pragma unroll
            for (int k = 0; k < 2; ++k) {      // rows: A <- J^T A
                const int id = lane + 64*k;
                const int m = id >> 4, j = id & 15;
                int p, q; pairpq(rr, m, p, q);
                const double cc = c8[m], ss = sn8[m];
                const double ap = Ad[p*17 + j], aq = Ad[q*17 + j];
                Ad[p*17 + j] = cc*ap - ss*aq;
                Ad[q*17 + j] = ss*ap + cc*aq;
            }
            #pragma unroll
            for (int k = 0; k < 2; ++k) {      // V <- V J
                const int id = lane + 64*k;
                const int m = id >> 4, i = id & 15;
                int p, q; pairpq(rr, m, p, q);
                const double cc = c8[m], ss = sn8[m];
                const double vp = Vd[i*17 + p], vq = Vd[i*17 + q];
                Vd[i*17 + p] = cc*vp - ss*vq;
                Vd[i*17 + q] = ss*vp + cc*vq;
            }
            wave_fence();
            #pragma unroll
            for (int k = 0; k < 2; ++k) {      // cols: A <- A J
                const int id = lane + 64*k;
                const int m = id >> 4, i = id & 15;
                int p, q; pairpq(rr, m, p, q);
                const double cc = c8[m], ss = sn8[m];
                const double ap = Ad[i*17 + p], aq = Ad[i*17 + q];
                Ad[i*17 + p] = cc*ap - ss*aq;
                Ad[i*17 + q] = ss*ap + cc*aq;
            }
            wave_fence();
        }
    }

    if (lane == 0) {
        double mx = 0.0;
        #pragma unroll
        for (int i = 0; i < 16; ++i) mx = fmax(mx, fabs(Ad[i*17 + i]));
        const double cut = JAX_RCOND * mx;
        #pragma unroll
        for (int i = 0; i < 16; ++i) {
            const double l = Ad[i*17 + i];
            il[i] = (fabs(l) > cut) ? (1.0 / l) : 0.0;
        }
    }
    wave_fence();

    if (lane < 16) {
        double a = 0.0;
        #pragma unroll
        for (int r = 0; r < 16; ++r) a += Vd[r*17 + lane] * (double)gaug[r*17 + 16];
        yv[lane] = a;
    }
    wave_fence();

    if (lane < 16) {
        double a = 0.0;
        #pragma unroll
        for (int i = 0; i < 16; ++i) a += Vd[lane*17 + i] * (il[i] * yv[i]);
        outp[lane] = (float)a;
    }
}

// Pre-kernel: W1T[j*32+i] = W1[i*512+j]   (64 KB, L2-resident afterwards)
extern "C" __global__ void w1_transpose(const float* __restrict__ W1,
                                        float* __restrict__ W1T) {
    const int t = blockIdx.x * 256 + threadIdx.x;
    W1T[t] = W1[(t & 31) * 512 + (t >> 5)];
}

// Pre-kernel: split W2 into 3 bf16 packs in MFMA B-fragment order (32x32x16).
extern "C" __global__ void w2_pack(const float* __restrict__ W2,
                                   uint* __restrict__ pHi,
                                   uint* __restrict__ pMid,
                                   uint* __restrict__ pLo) {
    const int tid = blockIdx.x * 256 + threadIdx.x;   // 0..32767
    const int lane = tid & 63;
    const int k0 = ((tid >> 6) & 31) * 16 + (lane >> 5) * 8;
    const int n  = (tid >> 11) * 32 + (lane & 31);
    uint h[4], m[4], l[4];
    #pragma unroll
    for (int e2 = 0; e2 < 4; ++e2) {
        ushort h0, m0, l0, h1, m1, l1;
        split3(W2[(k0 + 2*e2    )*512 + n], h0, m0, l0);
        split3(W2[(k0 + 2*e2 + 1)*512 + n], h1, m1, l1);
        h[e2] = (uint)h0 | ((uint)h1 << 16);
        m[e2] = (uint)m0 | ((uint)m1 << 16);
        l[e2] = (uint)l0 | ((uint)l1 << 16);
    }
    #pragma unroll
    for (int e2 = 0; e2 < 4; ++e2) {
        pHi [tid*4 + e2] = h[e2];
        pMid[tid*4 + e2] = m[e2];
        pLo [tid*4 + e2] = l[e2];
    }
}

#define MFMA32(A, B, C) __builtin_amdgcn_mfma_f32_32x32x16_bf16((A), (B), (C), 0, 0, 0)

extern "C" __global__ __launch_bounds__(256, 2)
void lnn_kernel(const float* __restrict__ x,
                const float* __restrict__ W1,
                const float* __restrict__ W1T,
                const float* __restrict__ b1,
                const float* __restrict__ W2, const float* __restrict__ b2,
                const float* __restrict__ W3,
                float* __restrict__ out,
                float* __restrict__ aug_g,
                const uint* __restrict__ pHi,
                const uint* __restrict__ pMid,
                const uint* __restrict__ pLo,
                const int solveInMain)
{
    const int b0 = blockIdx.x * 2;       // two samples: b0, b0+1
    const int t = threadIdx.x;
    const int lane = t & 63;
    const int w = t >> 6;

    extern __shared__ float sm[];
    char*  A8    = (char*)sm;          // A-splits, sample s at +s*24576
    float* s_ws  = sm + OFF_R;         // wsQ, sample s at +s*4096 floats
    char*  Mq8   = (char*)sm;          // MQ, sample s at +s*16896 bytes
    float* s_s1  = sm + OFF_S1;        // +s*512
    float* s_h1  = sm + OFF_H1;        // +s*512
    float* s_g2  = sm + OFF_G2;        // +s*512
    float* s_d2  = sm + OFF_D2;        // +s*512
    float* s_u   = sm + OFF_U;         // +s*512
    float* s_x   = sm + OFF_X;         // +s*32
    float* s_jac = sm + OFF_JAC;       // +s*16
    float* s_T1  = sm + OFF_T1;        // +s*528
    float* s_T2  = sm + OFF_T2;        // +s*528
    float* s_aug = sm + OFF_AUG;       // +s*272 (contiguous 544)

    // ---- P0 ----
    if (t < 64) s_x[t] = x[b0*32 + t];
    if (t < 32) {
        const int s = t >> 4, i = t & 15;
        out[(b0+s)*32 + i] = x[(b0+s)*32 + 16 + i];
    }
    __syncthreads();

    // ---- P1: z1 -> s1, h1 (coalesced W1T f4 reads; ascending-i order) ----
    #pragma unroll
    for (int rep = 0; rep < 4; ++rep) {
        const int s = rep >> 1;
        const int j = t + (rep & 1)*256;
        float z = b1[j];
        const f4* wt = (const f4*)(W1T + j*32);
        const float* xs = s_x + s*32;
        #pragma unroll
        for (int i4 = 0; i4 < 8; ++i4) {
            const f4 wv = wt[i4];
            z = fmaf(xs[i4*4 + 0], wv.x, z);
            z = fmaf(xs[i4*4 + 1], wv.y, z);
            z = fmaf(xs[i4*4 + 2], wv.z, z);
            z = fmaf(xs[i4*4 + 3], wv.w, z);
        }
        const float e = expf(-fabsf(z));
        const float sg = (z >= 0.f) ? 1.f/(1.f+e) : e/(1.f+e);
        s_s1[s*512 + j] = sg;
        s_h1[s*512 + j] = fmaxf(z, 0.f) + log1pf(e);
    }
    __syncthreads();

    // ---- z2 (EXACT fp32, original j-order, W2 loads shared by both samples) ----
    {
        const int c = w*128 + lane*2;
        const f2 bz = *(const f2*)(b2 + c);
        float za[2][2] = { {bz.x, bz.y}, {bz.x, bz.y} };
        #pragma unroll 8
        for (int j = 0; j < 512; ++j) {
            const f2 wv = *(const f2*)(W2 + j*512 + c);
            const float h0 = s_h1[j];
            const float h1 = s_h1[512 + j];
            za[0][0] = fmaf(h0, wv.x, za[0][0]);
            za[0][1] = fmaf(h0, wv.y, za[0][1]);
            za[1][0] = fmaf(h1, wv.x, za[1][0]);
            za[1][1] = fmaf(h1, wv.y, za[1][1]);
        }
        const f2 w3v = *(const f2*)(W3 + c);
        #pragma unroll
        for (int s = 0; s < 2; ++s) {
            const float e0 = expf(-fabsf(za[s][0]));
            const float sg0 = (za[s][0] >= 0.f) ? 1.f/(1.f+e0) : e0/(1.f+e0);
            const float e1v = expf(-fabsf(za[s][1]));
            const float sg1 = (za[s][1] >= 0.f) ? 1.f/(1.f+e1v) : e1v/(1.f+e1v);
            f2 g2v = { w3v.x * sg0, w3v.y * sg1 };
            f2 d2v = { w3v.x * sg0 * (1.f - sg0), w3v.y * sg1 * (1.f - sg1) };
            *(f2*)(s_g2 + s*512 + c) = g2v;
            *(f2*)(s_d2 + s*512 + c) = d2v;
        }
    }
    __syncthreads();

    // ---- P3: u[j] = W2[j,:] . g2 (4-way ILP x 2 samples; loads shared) ----
    {
        float g2a[8], g2b[8];
        {
            const float4 ga = *(const float4*)(s_g2 + lane*8);
            const float4 gb = *(const float4*)(s_g2 + lane*8 + 4);
            g2a[0]=ga.x; g2a[1]=ga.y; g2a[2]=ga.z; g2a[3]=ga.w;
            g2a[4]=gb.x; g2a[5]=gb.y; g2a[6]=gb.z; g2a[7]=gb.w;
            const float4 gc = *(const float4*)(s_g2 + 512 + lane*8);
            const float4 gd = *(const float4*)(s_g2 + 512 + lane*8 + 4);
            g2b[0]=gc.x; g2b[1]=gc.y; g2b[2]=gc.z; g2b[3]=gc.w;
            g2b[4]=gd.x; g2b[5]=gd.y; g2b[6]=gd.z; g2b[7]=gd.w;
        }
        for (int jj = 0; jj < 32; ++jj) {
            float pr0[4], pr1[4];
            #pragma unroll
            for (int s4 = 0; s4 < 4; ++s4) {
                const int j = w*128 + jj + s4*32;
                const float4 ra = *(const float4*)(W2 + j*512 + lane*8);
                const float4 rb = *(const float4*)(W2 + j*512 + lane*8 + 4);
                float p0 = ra.x*g2a[0];
                p0 = fmaf(ra.y, g2a[1], p0); p0 = fmaf(ra.z, g2a[2], p0); p0 = fmaf(ra.w, g2a[3], p0);
                p0 = fmaf(rb.x, g2a[4], p0); p0 = fmaf(rb.y, g2a[5], p0);
                p0 = fmaf(rb.z, g2a[6], p0); p0 = fmaf(rb.w, g2a[7], p0);
                pr0[s4] = p0;
                float p1 = ra.x*g2b[0];
                p1 = fmaf(ra.y, g2b[1], p1); p1 = fmaf(ra.z, g2b[2], p1); p1 = fmaf(ra.w, g2b[3], p1);
                p1 = fmaf(rb.x, g2b[4], p1); p1 = fmaf(rb.y, g2b[5], p1);
                p1 = fmaf(rb.z, g2b[6], p1); p1 = fmaf(rb.w, g2b[7], p1);
                pr1[s4] = p1;
            }
            #pragma unroll
            for (int off = 32; off >= 1; off >>= 1) {
                #pragma unroll
                for (int s4 = 0; s4 < 4; ++s4) {
                    pr0[s4] += __shfl_xor(pr0[s4], off);
                    pr1[s4] += __shfl_xor(pr1[s4], off);
                }
            }
            if (lane == 0) {
                #pragma unroll
                for (int s4 = 0; s4 < 4; ++s4) {
                    s_u[w*128 + jj + s4*32]       = pr0[s4];
                    s_u[512 + w*128 + jj + s4*32] = pr1[s4];
                }
            }
        }
    }
    __syncthreads();

    // ---- P4e: e1 = u(1-s1)/s1 into s_h1 ----
    #pragma unroll
    for (int rep = 0; rep < 4; ++rep) {
        const int j = (rep >> 1)*512 + t + (rep & 1)*256;
        const float uj = s_u[j], sv = s_s1[j];
        s_h1[j] = uj * (1.f - sv) / sv;
    }

    const int i5 = 16 + (t >> 4);
    const int c5 = 2 * (t & 15);

    // ---- P4/P5 quarter-staged: jac partials + term1 (both samples) ----
    {
        const f4* W1Tv4 = (const f4*)W1T;
        float jacp[2] = {0.f, 0.f};
        float t1a[2] = {0.f, 0.f}, t1b[2] = {0.f, 0.f};

        for (int q = 0; q < 4; ++q) {
            __syncthreads();   // q=0: e1 writes visible; q>0: wsQ reads done
            #pragma unroll
            for (int r = 0; r < 4; ++r) {
                const int f = r*256 + t;
                const f4 wv = W1Tv4[q*1024 + f];
                #pragma unroll
                for (int s = 0; s < 2; ++s) {
                    const float sv = s_s1[s*512 + q*128 + (f >> 3)];
                    f4 v = wv;
                    v.x*=sv; v.y*=sv; v.z*=sv; v.w*=sv;
                    ((f4*)(s_ws + s*4096))[f] = v;
                }
            }
            __syncthreads();

            if (w == q) {
                const int i  = t & 15;
                const int jb = (lane >> 4) * 32;
                #pragma unroll
                for (int s = 0; s < 2; ++s) {
                    const float* wsp = s_ws + s*4096;
                    const float* up  = s_u + s*512 + q*128;
                    float jp = jacp[s];
                    #pragma unroll 8
                    for (int jj = 0; jj < 32; ++jj)
                        jp = fmaf(wsp[(jb+jj)*32 + i], up[jb + jj], jp);
                    jacp[s] = jp;
                }
            }

            #pragma unroll
            for (int s = 0; s < 2; ++s) {
                const float* wsp = s_ws + s*4096;
                const float* ep  = s_h1 + s*512 + q*128;
                float a = t1a[s], bv = t1b[s];
                #pragma unroll 4
                for (int jj = 0; jj < 128; ++jj) {
                    const float e   = ep[jj];
                    const float wsi = wsp[jj*32 + i5];
                    const f2 wc = *(const f2*)(wsp + jj*32 + c5);
                    const float tt  = wsi * e;
                    a  = fmaf(tt, wc.x, a);
                    bv = fmaf(tt, wc.y, bv);
                }
                t1a[s] = a; t1b[s] = bv;
            }
        }
        #pragma unroll
        for (int s = 0; s < 2; ++s) {
            s_T1[s*528 + (i5-16)*33 + c5]     = t1a[s];
            s_T1[s*528 + (i5-16)*33 + c5 + 1] = t1b[s];
            s_g2[s*512 + (t>>4)*16 + (t&15)]  = jacp[s];   // g2 dead after P3
        }
    }
    __syncthreads();

    // fold jac (both samples)
    if (t < 32) {
        const int s = t >> 4, i = t & 15;
        float p = 0.f;
        #pragma unroll
        for (int seg = 0; seg < 16; ++seg) p += s_g2[s*512 + seg*16 + i];
        s_jac[s*16 + i] = p;
    }

    // ---- P2 single-pass: all 4 NTs x 2 samples (128 acc regs, 256-reg cap).
    //      A-splits staged once per quarter; packs streamed once. ----
    f32x16 s0n0{}, s0n1{}, s0n2{}, s0n3{};
    f32x16 s1n0{}, s1n1{}, s1n2{}, s1n3{};
    {
        const f4* W1v4 = (const f4*)W1;
        const f4* s1v4 = (const f4*)s_s1;
        const bf16x8* pHiV  = (const bf16x8*)pHi;
        const bf16x8* pMidV = (const bf16x8*)pMid;
        const bf16x8* pLoV  = (const bf16x8*)pLo;
        const int arow = lane & 31;
        const uint abase = (uint)arow * 256u;
        const uint aswz = (uint)(arow & 15);

        #pragma unroll 1
        for (int q = 0; q < 4; ++q) {
            __syncthreads();   // q=0: wsQ reads + jac fold done; q>0: A reads done
            // stage A-splits for both samples (W1 quarter loaded once)
            #pragma unroll
            for (int r = 0; r < 4; ++r) {
                const int f = r*256 + t;
                const int i = f >> 5, k4 = f & 31;
                const f4 wv = W1v4[i*128 + q*32 + k4];
                const uint off = (uint)i*256u + (((uint)k4*8u) ^ (((uint)(i & 15)) << 4));
                #pragma unroll
                for (int s = 0; s < 2; ++s) {
                    const f4 sv = s1v4[s*128 + q*32 + k4];
                    ushort h[4], m[4], l[4];
                    split3(wv.x*sv.x, h[0], m[0], l[0]);
                    split3(wv.y*sv.y, h[1], m[1], l[1]);
                    split3(wv.z*sv.z, h[2], m[2], l[2]);
                    split3(wv.w*sv.w, h[3], m[3], l[3]);
                    uint2v vh = { (uint)h[0] | ((uint)h[1]<<16), (uint)h[2] | ((uint)h[3]<<16) };
                    uint2v vm = { (uint)m[0] | ((uint)m[1]<<16), (uint)m[2] | ((uint)m[3]<<16) };
                    uint2v vl = { (uint)l[0] | ((uint)l[1]<<16), (uint)l[2] | ((uint)l[3]<<16) };
                    char* base = A8 + s*24576;
                    *(uint2v*)(base + off)         = vh;
                    *(uint2v*)(base + 8192 + off)  = vm;
                    *(uint2v*)(base + 16384 + off) = vl;
                }
            }
            __syncthreads();

            #pragma unroll 1
            for (int ks8 = 0; ks8 < 8; ++ks8) {
                const uint slot = (uint)(ks8*2 + (lane >> 5));
                const uint aoff = abase + ((slot ^ aswz) << 4);
                const bf16x8 aHi0  = *(const bf16x8*)(A8 + aoff);
                const bf16x8 aMid0 = *(const bf16x8*)(A8 + 8192 + aoff);
                const bf16x8 aLo0  = *(const bf16x8*)(A8 + 16384 + aoff);
                const bf16x8 aHi1  = *(const bf16x8*)(A8 + 24576 + aoff);
                const bf16x8 aMid1 = *(const bf16x8*)(A8 + 24576 + 8192 + aoff);
                const bf16x8 aLo1  = *(const bf16x8*)(A8 + 24576 + 16384 + aoff);
                const int pbase = (w*128 + q*8 + ks8)*64 + lane;
                #define KSTEP(A0, A1, NT) { \
                    const bf16x8 bHi  = pHiV [pbase + (NT)*2048]; \
                    const bf16x8 bMid = pMidV[pbase + (NT)*2048]; \
                    const bf16x8 bLo  = pLoV [pbase + (NT)*2048]; \
                    A0 = MFMA32(aHi0,  bHi,  A0); \
                    A0 = MFMA32(aHi0,  bMid, A0); \
                    A0 = MFMA32(aMid0, bHi,  A0); \
                    A0 = MFMA32(aMid0, bMid, A0); \
                    A0 = MFMA32(aHi0,  bLo,  A0); \
                    A0 = MFMA32(aLo0,  bHi,  A0); \
                    A1 = MFMA32(aHi1,  bHi,  A1); \
                    A1 = MFMA32(aHi1,  bMid, A1); \
                    A1 = MFMA32(aMid1, bHi,  A1); \
                    A1 = MFMA32(aMid1, bMid, A1); \
                    A1 = MFMA32(aHi1,  bLo,  A1); \
                    A1 = MFMA32(aLo1,  bHi,  A1); }
                KSTEP(s0n0, s1n0, 0)
                KSTEP(s0n1, s1n1, 1)
                KSTEP(s0n2, s1n2, 2)
                KSTEP(s0n3, s1n3, 3)
                #undef KSTEP
            }
        }
    }
    __syncthreads();   // all A-split reads done before MQ overwrites region R

    // ---- P7: term2 = M D2 M^T, 4 panel passes (full 32-qq order) ----
    {
        float h0acc[2] = {0.f, 0.f}, h1acc[2] = {0.f, 0.f};
        const int rowadd = 4 * (lane >> 5);
        const int cl = lane & 31;
        const uint swi = (uint)((i5 >> 1) & 7);
        const uint swc = (uint)((c5 >> 1) & 7);

        for (int p = 0; p < 4; ++p) {
            if (w == p) {   // wave p owns cols [p*128, p*128+128) in fragments
                #define WRFRAG(ACC, SOFF, NT) { \
                    _Pragma("unroll") \
                    for (int r = 0; r < 16; ++r) { \
                        const int row = (r & 3) + 8*(r >> 2) + rowadd; \
                        const int col = (NT)*32 + cl; \
                        const uint slot = ((uint)(col >> 2)) ^ ((uint)((row >> 1) & 7)); \
                        *(float*)(Mq8 + (SOFF) + row*528 + (slot << 4) + ((col & 3) << 2)) = ACC[r]; \
                    } }
                WRFRAG(s0n0, 0, 0)
                WRFRAG(s0n1, 0, 1)
                WRFRAG(s0n2, 0, 2)
                WRFRAG(s0n3, 0, 3)
                WRFRAG(s1n0, 16896, 0)
                WRFRAG(s1n1, 16896, 1)
                WRFRAG(s1n2, 16896, 2)
                WRFRAG(s1n3, 16896, 3)
                #undef WRFRAG
            }
            __syncthreads();
            #pragma unroll
            for (int s = 0; s < 2; ++s) {
                const f4* d2q = (const f4*)(s_d2 + s*512);
                const char* MiB = Mq8 + s*16896 + i5*528;
                const char* MaB = Mq8 + s*16896 + c5*528;
                const char* MbB = Mq8 + s*16896 + (c5+1)*528;
                float h0 = h0acc[s], h1v = h1acc[s];
                for (int qq = 0; qq < 32; ++qq) {
                    const f4 d  = d2q[p*32 + qq];
                    const f4 mi = *(const f4*)(MiB + (((uint)qq ^ swi) << 4));
                    const f4 ma = *(const f4*)(MaB + (((uint)qq ^ swc) << 4));
                    const f4 mb = *(const f4*)(MbB + (((uint)qq ^ swc) << 4));
                    float tt;
                    tt = mi.x*d.x; h0 = fmaf(tt, ma.x, h0); h1v = fmaf(tt, mb.x, h1v);
                    tt = mi.y*d.y; h0 = fmaf(tt, ma.y, h0); h1v = fmaf(tt, mb.y, h1v);
                    tt = mi.z*d.z; h0 = fmaf(tt, ma.z, h0); h1v = fmaf(tt, mb.z, h1v);
                    tt = mi.w*d.w; h0 = fmaf(tt, ma.w, h0); h1v = fmaf(tt, mb.w, h1v);
                }
                h0acc[s] = h0; h1acc[s] = h1v;
            }
            __syncthreads();   // reads done before next panel overwrites MQ
        }
        #pragma unroll
        for (int s = 0; s < 2; ++s) {
            s_T2[s*528 + (i5-16)*33 + c5]     = h0acc[s];
            s_T2[s*528 + (i5-16)*33 + c5 + 1] = h1acc[s];
        }
    }
    __syncthreads();

    // ---- P8: aug = [A | rhs] for both samples ----
    {
        const int r = t >> 4, c = t & 15;
        #pragma unroll
        for (int s = 0; s < 2; ++s)
            s_aug[s*272 + r*17 + c] = s_T1[s*528 + r*33 + 16 + c] + s_T2[s*528 + r*33 + 16 + c];
    }
    if (t < 32) {
        const int s = t >> 4, i = t & 15;
        float p = s_jac[s*16 + i];
        #pragma unroll
        for (int c = 0; c < 16; ++c)
            p -= (s_T1[s*528 + i*33 + c] + s_T2[s*528 + i*33 + c]) * s_x[s*32 + 16 + c];
        s_aug[s*272 + i*17 + 16] = p;
    }
    __syncthreads();

    if (!solveInMain) {
        // contiguous 544-float store (both samples)
        aug_g[b0*272 + t]       = s_aug[t];
        aug_g[b0*272 + 256 + t] = s_aug[256 + t];
        if (t < 32) aug_g[b0*272 + 512 + t] = s_aug[512 + t];
        return;
    }

    // Fallback: waves 0,1 solve samples 0,1
    if (w >= 2) return;
    jacobi_solve_wave(s_aug + w*272, (double*)sm + w*SOLVE_WAVE_DBL,
                      out + (b0+w)*32 + 16, lane);
}

extern "C" __global__ __launch_bounds__(256, 8)
void lnn_solve(const float* __restrict__ aug_g, float* __restrict__ out)
{
    const int t = threadIdx.x;
    const int lane = t & 63;
    const int w = t >> 6;
    const int b = blockIdx.x * 4 + w;

    extern __shared__ double dsm[];
    jacobi_solve_wave(aug_g + b*272, dsm + w*SOLVE_WAVE_DBL, out + b*32 + 16, lane);
}

extern "C" void kernel_launch(void* const* d_in, const int* in_sizes, int n_in,
                              void* d_out, int out_size, void* d_ws, size_t ws_size,
                              hipStream_t stream) {
    const float* x  = (const float*)d_in[0];
    const float* W1 = (const float*)d_in[1];
    const float* b1 = (const float*)d_in[2];
    const float* W2 = (const float*)d_in[3];
    const float* b2 = (const float*)d_in[4];
    const float* W3 = (const float*)d_in[5];
    float* out = (float*)d_out;

    float* W1T = (float*)d_ws;                             // 64 KB
    uint*  pHi  = (uint*)((char*)d_ws + 65536);
    uint*  pMid = (uint*)((char*)d_ws + 65536 + PACK_BYTES);
    uint*  pLo  = (uint*)((char*)d_ws + 65536 + 2*PACK_BYTES);
    float* aug  = (float*)((char*)d_ws + 65536 + 3*PACK_BYTES);
    const int bs = in_sizes[0] / 32;

    const size_t need = 65536 + 3*(size_t)PACK_BYTES + (size_t)bs * 272 * 4;
    const int solveInMain = (ws_size < need) ? 1 : 0;

    hipFuncSetAttribute((const void*)lnn_kernel,
                        hipFuncAttributeMaxDynamicSharedMemorySize, SMEM_BYTES);
    w1_transpose<<<dim3(64), dim3(256), 0, stream>>>(W1, W1T);
    w2_pack<<<dim3(128), dim3(256), 0, stream>>>(W2, pHi, pMid, pLo);
    lnn_kernel<<<dim3(bs/2), dim3(256), SMEM_BYTES, stream>>>(
        x, W1, W1T, b1, W2, b2, W3, out, aug, pHi, pMid, pLo, solveInMain);
    if (!solveInMain)
        lnn_solve<<<dim3(bs/4), dim3(256), SOLVE_SMEM_BYTES, stream>>>(aug, out);
}